// Round 1
// baseline (447.718 us; speedup 1.0000x reference)
//
#include <hip/hip_runtime.h>
#include <math.h>

// Problem: B=4096, T=256, D=64
//   mats[t] = expm(kernel * time[t])            (T x D x D)
//   out[b,t,i] = sum_j mats[t,i,j] * x0[b,j]    x0 = inputs[:,0,:]
//
// Phase 1 (expm_kernel): one WG per t, scaling-and-squaring + Taylor(10) in fp32
//   (numerics identical to previous version). NEW: prologue splits a slice of
//   x0 into bf16 hi/lo (Ah/Al), epilogue writes mats as bf16 hi/lo (Bh/Bl)
//   instead of fp32 G — conversion done once instead of per traj-WG.
// Phase 2 (traj_mfma): NO LDS, NO barriers. One wave per (t, 64-batch chunk).
//   MFMA operands loaded directly from the L2-resident split arrays in
//   fragment-native layout. Operand roles swapped vs previous version:
//   A=mats, B=x0 -> D[i][b], so each lane holds 4 CONSECUTIVE i values per
//   tile -> float4 stores (was 16 scalar dword stores/thread).

#define TT 256
#define DD 64
#define BB 4096
#define S1 68           // fp32 LDS row stride (words) for expm
#define THETA 0.5f
#define MTERMS 10

typedef __attribute__((ext_vector_type(8))) short short8;
typedef __attribute__((ext_vector_type(4))) float f32x4;

// split fp32 into bf16 hi (RN) + bf16 lo (trunc of residual); x ~ hi+lo, |eps|<~2^-17|x|
__device__ __forceinline__ void bf16_split(float x, unsigned short& hi, unsigned short& lo) {
    union { float f; unsigned int u; } a; a.f = x;
    unsigned int r = (a.u + 0x7fffu + ((a.u >> 16) & 1u)) & 0xffff0000u;  // RN to bf16
    hi = (unsigned short)(r >> 16);
    union { float f; unsigned int u; } d; d.f = x - __uint_as_float(r);
    lo = (unsigned short)(d.u >> 16);  // truncation of residual
}

// ---------------- expm phase ----------------

// C[i][j] = f * sum_k Lt[k*S1+i] * R[k*S1+j]   (C = Lt^T * R, all stride S1)
__device__ __forceinline__ void mm68(const float* __restrict__ Lt,
                                     const float* __restrict__ R,
                                     float* __restrict__ C,
                                     float f, float* __restrict__ Eacc, int tid) {
    const int i0 = (tid & 15) * 4;
    const int j0 = (tid >> 4) * 4;
    float acc[4][4];
#pragma unroll
    for (int r = 0; r < 4; ++r)
#pragma unroll
        for (int c = 0; c < 4; ++c) acc[r][c] = 0.f;

#pragma unroll 8
    for (int k = 0; k < 64; ++k) {
        const float4 a = *reinterpret_cast<const float4*>(&Lt[k * S1 + i0]);
        const float4 b = *reinterpret_cast<const float4*>(&R[k * S1 + j0]);
        const float av[4] = {a.x, a.y, a.z, a.w};
        const float bv[4] = {b.x, b.y, b.z, b.w};
#pragma unroll
        for (int r = 0; r < 4; ++r)
#pragma unroll
            for (int c = 0; c < 4; ++c) acc[r][c] = fmaf(av[r], bv[c], acc[r][c]);
    }

#pragma unroll
    for (int r = 0; r < 4; ++r) {
        float4 v;
        v.x = acc[r][0] * f; v.y = acc[r][1] * f; v.z = acc[r][2] * f; v.w = acc[r][3] * f;
        *reinterpret_cast<float4*>(&C[(i0 + r) * S1 + j0]) = v;
        if (Eacc) {
            float* e = &Eacc[(i0 + r) * S1 + j0];
            e[0] += v.x; e[1] += v.y; e[2] += v.z; e[3] += v.w;
        }
    }
}

__device__ __forceinline__ void transpose68(const float* __restrict__ X,
                                            float* __restrict__ XT, int tid) {
    const int i = tid >> 2;
    const int j0 = (tid & 3) * 16;
#pragma unroll
    for (int c4 = 0; c4 < 4; ++c4) {
        const float4 v = *reinterpret_cast<const float4*>(&X[i * S1 + j0 + 4 * c4]);
        XT[(j0 + 4 * c4 + 0) * S1 + i] = v.x;
        XT[(j0 + 4 * c4 + 1) * S1 + i] = v.y;
        XT[(j0 + 4 * c4 + 2) * S1 + i] = v.z;
        XT[(j0 + 4 * c4 + 3) * S1 + i] = v.w;
    }
}

__global__ __launch_bounds__(256)
void expm_kernel(const float* __restrict__ K, const float* __restrict__ tim,
                 const float* __restrict__ inputs,
                 unsigned short* __restrict__ Bh, unsigned short* __restrict__ Bl,
                 unsigned short* __restrict__ Ah, unsigned short* __restrict__ Al) {
    __shared__ float As[64 * S1];
    __shared__ float Pa[64 * S1];
    __shared__ float Pb[64 * S1];
    __shared__ float Et[64 * S1];
    __shared__ float Tx[64 * S1];
    __shared__ float red[64];

    const int tid = threadIdx.x;
    const int t = blockIdx.x;
    const float tval = tim[t];

    // x0 split prologue: WG t handles elements [t*1024, t*1024+1024) of [4096][64]
    {
        const int idx = t * 1024 + tid * 4;
        const int b = idx >> 6;
        const int j = idx & 63;
        const float4 v = *reinterpret_cast<const float4*>(inputs + (size_t)b * (TT * DD) + j);
        ushort4 h, l;
        bf16_split(v.x, h.x, l.x); bf16_split(v.y, h.y, l.y);
        bf16_split(v.z, h.z, l.z); bf16_split(v.w, h.w, l.w);
        *reinterpret_cast<ushort4*>(&Ah[b * 64 + j]) = h;
        *reinterpret_cast<ushort4*>(&Al[b * 64 + j]) = l;
    }

    if (tid < 64) {
        float s = 0.f;
        for (int j = 0; j < 64; ++j) s += fabsf(K[tid * 64 + j]);
        red[tid] = s;
    }
    __syncthreads();
    if (tid == 0) {
        float m = 0.f;
        for (int i = 0; i < 64; ++i) m = fmaxf(m, red[i]);
        const float nt = m * tval;
        int s = 0;
        if (nt > THETA) {
            s = (int)ceilf(log2f(nt / THETA));
            if (s < 0) s = 0;
        }
        red[0] = ldexpf(tval, -s);
        red[1] = (float)s;
    }
    __syncthreads();
    const float scale = red[0];
    const int sq = (int)red[1];
    __syncthreads();

    // As = K*scale ; Pa = As^T (=P1^T) ; Et = I^T + As^T
    {
        const int i = tid >> 2;
        const int j0 = (tid & 3) * 16;
#pragma unroll
        for (int c = 0; c < 16; ++c) {
            const int j = j0 + c;
            const float v = K[i * 64 + j] * scale;
            As[i * S1 + j] = v;
            Pa[j * S1 + i] = v;
            Et[j * S1 + i] = v + ((i == j) ? 1.f : 0.f);
        }
    }
    __syncthreads();

    float* Pcur = Pa;
    float* Pnext = Pb;
    for (int n = 2; n <= MTERMS; ++n) {
        mm68(As, Pcur, Pnext, 1.0f / (float)n, Et, tid);
        __syncthreads();
        float* tmp = Pcur; Pcur = Pnext; Pnext = tmp;
    }

    transpose68(Et, Tx, tid);     // Tx = E (row-major [i][j])
    __syncthreads();
    float* cur = Tx;
    float* nxt = Pa;
    const float* curT = Et;
    for (int r = 0; r < sq; ++r) {
        if (r > 0) {
            transpose68(cur, Pb, tid);
            __syncthreads();
            curT = Pb;
        }
        mm68(curT, cur, nxt, 1.f, nullptr, tid);
        __syncthreads();
        float* tmp = cur; cur = nxt; nxt = tmp;
    }

    // epilogue: Bh/Bl[t][i][j] = bf16_split(cur[i][j])  (row-major, fragment-native)
    {
        const int i = tid >> 2;
        const int j0 = (tid & 3) * 16;
        unsigned short* oh = Bh + (size_t)t * 4096 + i * 64 + j0;
        unsigned short* ol = Bl + (size_t)t * 4096 + i * 64 + j0;
#pragma unroll
        for (int c4 = 0; c4 < 4; ++c4) {
            const float4 v = *reinterpret_cast<const float4*>(&cur[i * S1 + j0 + 4 * c4]);
            ushort4 h, l;
            bf16_split(v.x, h.x, l.x); bf16_split(v.y, h.y, l.y);
            bf16_split(v.z, h.z, l.z); bf16_split(v.w, h.w, l.w);
            *reinterpret_cast<ushort4*>(oh + 4 * c4) = h;
            *reinterpret_cast<ushort4*>(ol + 4 * c4) = l;
        }
    }
}

// ---------------- traj phase (MFMA, LDS-free) ----------------

// One WG = 4 waves. Wave w: t = blockIdx.x & 255, b rows
// [bg*256 + w*64, +64) in 4 tiles of 16. D[i][b] per MFMA:
// lane holds col b = l&15, rows i = (l>>4)*4 + reg -> float4 store.
__global__ __launch_bounds__(256)
void traj_mfma(const unsigned short* __restrict__ Ah, const unsigned short* __restrict__ Al,
               const unsigned short* __restrict__ Bh, const unsigned short* __restrict__ Bl,
               float* __restrict__ out) {
    const int tid = threadIdx.x;
    const int t  = blockIdx.x & (TT - 1);
    const int bg = blockIdx.x >> 8;        // 0..15
    const int w  = tid >> 6;               // wave id
    const int l  = tid & 63;
    const int ln = l & 15;
    const int qd = l >> 4;                 // 0..3

    // mats fragments (MFMA A-operand): row i = m*16+ln, k = kh*32 + qd*8
    const unsigned short* mh = Bh + (size_t)t * 4096;
    const unsigned short* ml = Bl + (size_t)t * 4096;
    short8 Mh[4][2], Ml[4][2];
#pragma unroll
    for (int m = 0; m < 4; ++m)
#pragma unroll
        for (int kh = 0; kh < 2; ++kh) {
            const int off = (m * 16 + ln) * 64 + kh * 32 + qd * 8;
            Mh[m][kh] = *reinterpret_cast<const short8*>(mh + off);
            Ml[m][kh] = *reinterpret_cast<const short8*>(ml + off);
        }

    const int brow0 = bg * 256 + w * 64;
#pragma unroll
    for (int it = 0; it < 4; ++it) {
        const int brow = brow0 + it * 16 + ln;

        // x0 fragments (MFMA B-operand): col b = ln, k = kh*32 + qd*8
        short8 Xh[2], Xl[2];
#pragma unroll
        for (int kh = 0; kh < 2; ++kh) {
            const int aoff = brow * 64 + kh * 32 + qd * 8;
            Xh[kh] = *reinterpret_cast<const short8*>(Ah + aoff);
            Xl[kh] = *reinterpret_cast<const short8*>(Al + aoff);
        }

        f32x4 acc[4];
#pragma unroll
        for (int m = 0; m < 4; ++m) acc[m] = (f32x4){0.f, 0.f, 0.f, 0.f};

#pragma unroll
        for (int kh = 0; kh < 2; ++kh)
#pragma unroll
            for (int m = 0; m < 4; ++m) {
                acc[m] = __builtin_amdgcn_mfma_f32_16x16x32_bf16(Mh[m][kh], Xh[kh], acc[m], 0, 0, 0);
                acc[m] = __builtin_amdgcn_mfma_f32_16x16x32_bf16(Ml[m][kh], Xh[kh], acc[m], 0, 0, 0);
                acc[m] = __builtin_amdgcn_mfma_f32_16x16x32_bf16(Mh[m][kh], Xl[kh], acc[m], 0, 0, 0);
            }

        // out[brow][t][m*16 + qd*4 + r] = acc[m][r]  -> one float4 per m
        float* obase = out + (size_t)brow * (TT * DD) + (size_t)t * DD + qd * 4;
#pragma unroll
        for (int m = 0; m < 4; ++m) {
            float4 v;
            v.x = acc[m][0]; v.y = acc[m][1]; v.z = acc[m][2]; v.w = acc[m][3];
            *reinterpret_cast<float4*>(obase + m * 16) = v;
        }
    }
}

extern "C" void kernel_launch(void* const* d_in, const int* in_sizes, int n_in,
                              void* d_out, int out_size, void* d_ws, size_t ws_size,
                              hipStream_t stream) {
    const float* inputs = (const float*)d_in[0];
    const float* tim    = (const float*)d_in[1];
    const float* K      = (const float*)d_in[2];
    float* out = (float*)d_out;

    // workspace layout (5 MB total): Bh | Bl (2 MB each) | Ah | Al (512 KB each)
    unsigned short* Bh = (unsigned short*)d_ws;
    unsigned short* Bl = Bh + (size_t)TT * DD * DD;
    unsigned short* Ah = Bl + (size_t)TT * DD * DD;
    unsigned short* Al = Ah + (size_t)BB * DD;

    expm_kernel<<<TT, 256, 0, stream>>>(K, tim, inputs, Bh, Bl, Ah, Al);
    traj_mfma<<<(BB / 256) * TT, 256, 0, stream>>>(Ah, Al, Bh, Bl, out);
}